// Round 11
// baseline (624.192 us; speedup 1.0000x reference)
//
#include <hip/hip_runtime.h>
#include <math.h>

typedef short bf16x8 __attribute__((ext_vector_type(8)));
typedef short bf16x4 __attribute__((ext_vector_type(4)));
typedef float f32x4  __attribute__((ext_vector_type(4)));

#define TT 32
#define MM 16
#define CC 128
#define NPT 32768
#define NC 4194304          // NPT*CC, elements per time-slice
#define BN 8                // n-points per block

// ---- LDS layout (bytes), total 77824 (76 KB) -> 2 blocks/CU ----
// XF : bf16 [m16][n8][i128][ri2] = 65536 B, phys = L ^ ((n&7)<<4)
// OF : bf16 [no128][k2_32] rows 64 B, byte-in-row b -> b ^ ((no&7)<<3)  (8 KB)
// SCR: tabc/tabs f32[512] (4 KB) during DFT; first 2 KB rewritten as DT bf16
//      [t32][k2_32] (row 64 B, b ^ ((t&7)<<3)) after the DFT phase.
#define XF_OFF   0
#define OF_OFF   65536
#define SCR_OFF  73728
#define LDS_BYTES 77824

static __device__ __forceinline__ unsigned short f2bf(float f) {
    union { float f; unsigned u; } v; v.f = f;
    unsigned r = v.u + 0x7FFFu + ((v.u >> 16) & 1u);   // RNE
    return (unsigned short)(r >> 16);
}
static __device__ __forceinline__ unsigned pack2(float lo, float hi) {
    return (unsigned)f2bf(lo) | ((unsigned)f2bf(hi) << 16);
}

// ============================================================================
// Weight repack: w[i][o][m][ri] f32 -> bf16 MFMA B-fragments in d_ws.
// Layout (short8 rows): WB[m][og][riOut][ck][lane] — per (m,og) contiguous 16 KB.
// Row holds B[k = ck*32 + (lane>>4)*8 + j][o = og*16 + (lane&15)], j=0..7,
// k = 2i+ri_in stacking:  B_R = {+Wr, -Wi},  B_I = {+Wi, +Wr}.
// ============================================================================
__global__ void repack_w(const float* __restrict__ w, bf16x8* __restrict__ wb) {
    int r = blockIdx.x * blockDim.x + threadIdx.x;    // 0..131071
    int lane = r & 63;
    int r2 = r >> 6;
    int ck = r2 & 7;
    int r3 = r2 >> 3;
    int ri = r3 & 1;
    int r4 = r3 >> 1;
    int og = r4 & 7;
    int m  = r4 >> 3;
    int o = og * 16 + (lane & 15);
    int kbase = ck * 32 + (lane >> 4) * 8;
    bf16x8 v;
    #pragma unroll
    for (int j = 0; j < 8; ++j) {
        int k = kbase + j;
        int i = k >> 1, ko = k & 1;
        const float* wp = w + ((size_t)(i * 128 + o) * 16 + m) * 2;
        float val;
        if (ri == 0) val = ko ? -wp[1] : wp[0];
        else         val = ko ?  wp[0] : wp[1];
        v[j] = (short)f2bf(val);
    }
    wb[r] = v;
}

// ============================================================================
// Main fused kernel: 4096 blocks x 1024 threads (16 waves), BN=8,
// 76 KB LDS + VGPR<=64 -> 2 blocks/CU (R4-proven residency shape).
// einsum: wave = mode; M-rows 8..15 alias 0..7 (outputs discarded, kq<2 gate).
// irfft: wave w -> (t-half w>>3, n-row w&7); DT matrix in LDS, hoisted.
// ============================================================================
__global__ __launch_bounds__(1024, 2)
void spectral_mfma(const float* __restrict__ x, const bf16x8* __restrict__ wb,
                   float* __restrict__ out) {
    extern __shared__ char lds[];
    float* tabc = (float*)(lds + SCR_OFF);          // SCR[0:2048]
    float* tabs = (float*)(lds + SCR_OFF + 2048);   // SCR[2048:4096]
    char*  dtb  = lds + SCR_OFF;                    // DT overlays tabc later
    const int tid = threadIdx.x;
    const int n0  = blockIdx.x * BN;

    // ---------- phase 0: rfft tables [t][m] ----------
    if (tid < 512) {
        int m = tid & 15, t = tid >> 4;
        float s, c;
        sincosf(0.19634954084936207f * (float)((m * t) & 31), &s, &c);
        tabc[t * 16 + m] = c;
        tabs[t * 16 + m] = s;
    }
    __syncthreads();

    // ---------- phase 1: folded rfft, ONE i-column per thread (32 accums) ----
    {
        const int nn = tid >> 7;            // 0..7
        const int i  = tid & 127;
        const float* xp = x + (size_t)(n0 + nn) * CC + i;
        float x0  = xp[0];
        float x16 = xp[(size_t)16 * NC];
        float xr[16], xi[16];
        #pragma unroll
        for (int m = 0; m < 16; ++m) {
            xr[m] = x0 + ((m & 1) ? -x16 : x16);
            xi[m] = 0.f;
        }
        #pragma unroll 3
        for (int t = 1; t <= 15; ++t) {
            float a = xp[(size_t)t * NC];
            float b = xp[(size_t)(32 - t) * NC];
            float e = a + b, od = a - b;
            float4 c0 = *(const float4*)&tabc[t * 16 + 0];
            float4 c1 = *(const float4*)&tabc[t * 16 + 4];
            float4 c2 = *(const float4*)&tabc[t * 16 + 8];
            float4 c3 = *(const float4*)&tabc[t * 16 + 12];
            float4 s0 = *(const float4*)&tabs[t * 16 + 0];
            float4 s1 = *(const float4*)&tabs[t * 16 + 4];
            float4 s2 = *(const float4*)&tabs[t * 16 + 8];
            float4 s3 = *(const float4*)&tabs[t * 16 + 12];
            float cm[16] = {c0.x,c0.y,c0.z,c0.w, c1.x,c1.y,c1.z,c1.w,
                            c2.x,c2.y,c2.z,c2.w, c3.x,c3.y,c3.z,c3.w};
            float sm[16] = {s0.x,s0.y,s0.z,s0.w, s1.x,s1.y,s1.z,s1.w,
                            s2.x,s2.y,s2.z,s2.w, s3.x,s3.y,s3.z,s3.w};
            #pragma unroll
            for (int m = 0; m < 16; ++m) {
                xr[m] += e * cm[m];
                xi[m] -= od * sm[m];
            }
        }
        char* xfb = lds + XF_OFF;
        const unsigned swzd = (unsigned)((nn & 7) << 4);
        #pragma unroll
        for (int m = 0; m < 16; ++m) {
            unsigned byte = ((unsigned)(m * 4096 + nn * 512 + i * 4)) ^ swzd;
            *(unsigned*)(xfb + byte) = pack2(xr[m], xi[m]);
        }
    }
    __syncthreads();   // all table reads done; SCR can be rewritten as DT

    // ---------- phase 2: irfft matrix DT[t][k2] bf16 into SCR ----------
    {
        int t = tid >> 5, k2 = tid & 31, m = k2 >> 1, ri = k2 & 1;
        float alpha = (m == 0) ? 0.03125f : 0.0625f;   // 1/32, 2/32
        float s, c;
        sincosf(0.19634954084936207f * (float)((m * t) & 31), &s, &c);
        float val = (ri == 0) ? alpha * c : -alpha * s;
        if (m == 0 && ri == 1) val = 0.f;              // c2r ignores imag of bin 0
        unsigned addr = ((unsigned)(t * 64 + k2 * 2)) ^ ((unsigned)((t & 7) << 3));
        *(unsigned short*)(dtb + addr) = f2bf(val);
    }
    __syncthreads();

    // ---------- phase 3: og loop — einsum + irfft ----------
    const int lane = tid & 63;
    const int wid  = tid >> 6;          // einsum: mode; irfft: (t-half, n-row)
    const int col  = lane & 15;
    const int kq   = lane >> 4;
    const int th   = wid >> 3;          // t-half for irfft
    const int nn_i = wid & 7;           // n-row for irfft
    const unsigned swza = (unsigned)((col & 7) << 4);
    const unsigned swzo = (unsigned)((col & 7) << 3);
    const unsigned arow = (unsigned)(wid * 4096 + (col & 7) * 512 + kq * 16);

    // hoist irfft A-fragment: DT[t = th*16+col][k2 = kq*8 + q]  (4 VGPR)
    bf16x8 dtf;
    {
        unsigned row = (unsigned)(th * 16 + col);
        unsigned a0 = (row * 64u + (unsigned)(kq * 16))     ^ ((row & 7) << 3);
        unsigned a1 = (row * 64u + (unsigned)(kq * 16 + 8)) ^ ((row & 7) << 3);
        bf16x4 lo = *(const bf16x4*)(dtb + a0);
        bf16x4 hi = *(const bf16x4*)(dtb + a1);
        #pragma unroll
        for (int q = 0; q < 4; ++q) { dtf[q] = lo[q]; dtf[4 + q] = hi[q]; }
    }

    char* xfb = lds + XF_OFF;
    char* ofb = lds + OF_OFF;
    float* outp = out + (size_t)(n0 + nn_i) * CC + col;
    f32x4 sv = {0.f, 0.f, 0.f, 0.f};

    for (int k = 0; k < 8; ++k) {
        // --- einsum: OF[mode=wid], o-tile k, K=256 over (i,ri), M=8 valid ---
        const bf16x8* wog = wb + (size_t)((wid * 8 + k) * 2) * (8 * 64);
        f32x4 accR = {0.f, 0.f, 0.f, 0.f};
        f32x4 accI = {0.f, 0.f, 0.f, 0.f};
        #pragma unroll
        for (int ck = 0; ck < 8; ++ck) {
            bf16x8 af = *(const bf16x8*)(xfb + ((arow + (unsigned)(ck * 64)) ^ swza));
            bf16x8 bR = wog[(0 * 8 + ck) * 64 + lane];
            bf16x8 bI = wog[(1 * 8 + ck) * 64 + lane];
            accR = __builtin_amdgcn_mfma_f32_16x16x32_bf16(af, bR, accR, 0, 0, 0);
            accI = __builtin_amdgcn_mfma_f32_16x16x32_bf16(af, bI, accI, 0, 0, 0);
        }
        if (kq < 2) {                    // rows n = kq*4+j < 8 valid
            #pragma unroll
            for (int j = 0; j < 4; ++j) {
                unsigned no = (unsigned)((kq * 4 + j) * 16 + col);
                unsigned addr = no * 64u + (((unsigned)(wid * 4)) ^ ((no & 7) << 3));
                *(unsigned*)(ofb + addr) = pack2(accR[j], accI[j]);
            }
        }
        __syncthreads();
        // --- irfft: wave (th, nn_i); 1 MFMA; og-pair buffered stores ---
        {
            unsigned row = (unsigned)(nn_i * 16 + col);        // row&7 == col&7
            bf16x4 lo = *(const bf16x4*)(ofb + row * 64u + (((unsigned)(kq * 16))     ^ swzo));
            bf16x4 hi = *(const bf16x4*)(ofb + row * 64u + (((unsigned)(kq * 16 + 8)) ^ swzo));
            bf16x8 pf;
            #pragma unroll
            for (int q = 0; q < 4; ++q) { pf[q] = lo[q]; pf[4 + q] = hi[q]; }
            f32x4 z = {0.f, 0.f, 0.f, 0.f};
            f32x4 cc = __builtin_amdgcn_mfma_f32_16x16x32_bf16(dtf, pf, z, 0, 0, 0);
            if ((k & 1) == 0) {
                sv = cc;                 // buffer even og; store with odd og
            } else {
                float* opE = outp + (k - 1) * 16;
                float* opO = outp + k * 16;
                #pragma unroll
                for (int j = 0; j < 4; ++j) {
                    int t0 = th * 16 + kq * 4 + j;
                    opE[(size_t)t0 * NC] = sv[j];    // adjacent 64B halves of
                    opO[(size_t)t0 * NC] = cc[j];    // one 128B line
                }
            }
        }
        __syncthreads();   // OF reused next og
    }
}

// ============================================================================
// Fallback (round-1 proven kernel) — used only if ws_size < 2 MB.
// ============================================================================
#define FBN 8
#define FXST 36
__global__ __launch_bounds__(512, 2)
void spectral_fused(const float* __restrict__ x,
                    const float* __restrict__ w,
                    float* __restrict__ out) {
    extern __shared__ float flds[];
    float* xf    = flds;
    float* ftabc = flds + FBN * CC * FXST;
    float* ftabs = ftabc + 512;

    const int tid = threadIdx.x;
    const int n0  = blockIdx.x * FBN;

    {
        const int m = tid >> 5;
        const int t = tid & 31;
        const float ang = 0.19634954084936207f * (float)((m * t) & 31);
        float s, c; sincosf(ang, &s, &c);
        ftabc[tid] = c; ftabs[tid] = s;
    }
    __syncthreads();
    {
        const int i   = tid & 127;
        const int nnA = tid >> 7;
        const int nnB = nnA + 4;
        float xra[MM], xia[MM], xrb[MM], xib[MM];
        #pragma unroll
        for (int m = 0; m < MM; ++m) { xra[m]=0.f; xia[m]=0.f; xrb[m]=0.f; xib[m]=0.f; }
        const float* xA = x + (size_t)(n0 + nnA) * CC + i;
        const float* xB = x + (size_t)(n0 + nnB) * CC + i;
        for (int t = 0; t < TT; ++t) {
            const float va = xA[(size_t)t * NC];
            const float vb = xB[(size_t)t * NC];
            #pragma unroll
            for (int m = 0; m < MM; ++m) {
                const float c = ftabc[(m << 5) + t];
                const float s = ftabs[(m << 5) + t];
                xra[m] += va * c;  xia[m] -= va * s;
                xrb[m] += vb * c;  xib[m] -= vb * s;
            }
        }
        float* dA = xf + (size_t)(nnA * CC + i) * FXST;
        float* dB = xf + (size_t)(nnB * CC + i) * FXST;
        #pragma unroll
        for (int j = 0; j < 8; ++j) {
            *(float4*)(dA + 4 * j) = make_float4(xra[2*j], xia[2*j], xra[2*j+1], xia[2*j+1]);
            *(float4*)(dB + 4 * j) = make_float4(xrb[2*j], xib[2*j], xrb[2*j+1], xib[2*j+1]);
        }
    }
    __syncthreads();
    const int o   = tid & 127;
    const int nnA = tid >> 7;
    const int nnB = nnA + 4;
    float ar[MM], ai_[MM], br[MM], bi_[MM];
    #pragma unroll
    for (int m = 0; m < MM; ++m) { ar[m]=0.f; ai_[m]=0.f; br[m]=0.f; bi_[m]=0.f; }
    const float* qa0 = xf + (size_t)(nnA * CC) * FXST;
    const float* qb0 = xf + (size_t)(nnB * CC) * FXST;
    float4 wv[8];
    {
        const float4* wp = (const float4*)(w + (size_t)o * 32);
        #pragma unroll
        for (int j = 0; j < 8; ++j) wv[j] = wp[j];
    }
    for (int i = 0; i < CC; ++i) {
        float4 xa4[8], xb4[8];
        const float4* qa = (const float4*)(qa0 + i * FXST);
        const float4* qb = (const float4*)(qb0 + i * FXST);
        #pragma unroll
        for (int j = 0; j < 8; ++j) { xa4[j] = qa[j]; xb4[j] = qb[j]; }
        float4 wn[8];
        if (i + 1 < CC) {
            const float4* wp = (const float4*)(w + (size_t)((i + 1) * CC + o) * 32);
            #pragma unroll
            for (int j = 0; j < 8; ++j) wn[j] = wp[j];
        }
        #pragma unroll
        for (int j = 0; j < 8; ++j) {
            const int m0 = 2 * j, m1 = 2 * j + 1;
            ar[m0]  += xa4[j].x * wv[j].x - xa4[j].y * wv[j].y;
            ai_[m0] += xa4[j].x * wv[j].y + xa4[j].y * wv[j].x;
            br[m0]  += xb4[j].x * wv[j].x - xb4[j].y * wv[j].y;
            bi_[m0] += xb4[j].x * wv[j].y + xb4[j].y * wv[j].x;
            ar[m1]  += xa4[j].z * wv[j].z - xa4[j].w * wv[j].w;
            ai_[m1] += xa4[j].z * wv[j].w + xa4[j].w * wv[j].z;
            br[m1]  += xb4[j].z * wv[j].z - xb4[j].w * wv[j].w;
            bi_[m1] += xb4[j].z * wv[j].w + xb4[j].w * wv[j].z;
        }
        #pragma unroll
        for (int j = 0; j < 8; ++j) wv[j] = wn[j];
    }
    {
        const float inv = 1.0f / 32.0f;
        const size_t obA = (size_t)(n0 + nnA) * CC + o;
        const size_t obB = (size_t)(n0 + nnB) * CC + o;
        for (int t = 0; t < TT; ++t) {
            float accA = 0.f, accB = 0.f;
            #pragma unroll
            for (int m = 1; m < MM; ++m) {
                const float c = ftabc[(m << 5) + t];
                const float s = ftabs[(m << 5) + t];
                accA += ar[m] * c - ai_[m] * s;
                accB += br[m] * c - bi_[m] * s;
            }
            out[(size_t)t * NC + obA] = (ar[0] + 2.f * accA) * inv;
            out[(size_t)t * NC + obB] = (br[0] + 2.f * accB) * inv;
        }
    }
}

extern "C" void kernel_launch(void* const* d_in, const int* in_sizes, int n_in,
                              void* d_out, int out_size, void* d_ws, size_t ws_size,
                              hipStream_t stream) {
    (void)in_sizes; (void)n_in; (void)out_size;
    const float* x = (const float*)d_in[0];
    const float* w = (const float*)d_in[1];
    float* out     = (float*)d_out;

    if (d_ws != nullptr && ws_size >= (size_t)2 * 1024 * 1024) {
        bf16x8* wbuf = (bf16x8*)d_ws;
        hipLaunchKernelGGL(repack_w, dim3(512), dim3(256), 0, stream, w, wbuf);
        hipLaunchKernelGGL(spectral_mfma, dim3(NPT / BN), dim3(1024), LDS_BYTES, stream,
                           x, wbuf, out);
    } else {
        const size_t lds_bytes = (size_t)(FBN * CC * FXST + 1024) * sizeof(float);
        hipLaunchKernelGGL(spectral_fused, dim3(NPT / FBN), dim3(512), lds_bytes, stream,
                           x, w, out);
    }
}

// Round 12
// 444.640 us; speedup vs baseline: 1.4038x; 1.4038x over previous
//
#include <hip/hip_runtime.h>
#include <math.h>

typedef short bf16x8 __attribute__((ext_vector_type(8)));
typedef short bf16x4 __attribute__((ext_vector_type(4)));
typedef float f32x4  __attribute__((ext_vector_type(4)));

#define TT 32
#define MM 16
#define CC 128
#define NPT 32768
#define NC 4194304          // NPT*CC, elements per time-slice
#define BN 16               // n-points per block

// ---- LDS layout (bytes), total 163840 = 160 KiB exactly ----
// XF : bf16 [m16][n16][i128][ri2] = 131072 B, phys = L ^ ((n&7)<<4)
// OF0/OF1 : bf16 [no256][k2_32], row stride 64 B, byte-in-row b -> b ^ ((no&7)<<3)
// rfft tables (f32[512] x2 = 4 KB) OVERLAY OF1[0:4096] (dead until og k=1)
#define XF_OFF   0
#define OF0_OFF  131072
#define OF1_OFF  147456
#define LDS_BYTES 163840

static __device__ __forceinline__ unsigned short f2bf(float f) {
    union { float f; unsigned u; } v; v.f = f;
    unsigned r = v.u + 0x7FFFu + ((v.u >> 16) & 1u);   // RNE
    return (unsigned short)(r >> 16);
}
static __device__ __forceinline__ unsigned pack2(float lo, float hi) {
    return (unsigned)f2bf(lo) | ((unsigned)f2bf(hi) << 16);
}

// ============================================================================
// Weight repack: w[i][o][m][ri] f32 -> bf16 MFMA B-fragments in d_ws.
// Layout (short8 rows): WB[m][og][riOut][ck][lane] — per (m,og) contiguous 16 KB.
// Row holds B[k = ck*32 + (lane>>4)*8 + j][o = og*16 + (lane&15)], j=0..7,
// k = 2i+ri_in stacking:  B_R = {+Wr, -Wi},  B_I = {+Wi, +Wr}.
// ============================================================================
__global__ void repack_w(const float* __restrict__ w, bf16x8* __restrict__ wb) {
    int r = blockIdx.x * blockDim.x + threadIdx.x;    // 0..131071
    int lane = r & 63;
    int r2 = r >> 6;
    int ck = r2 & 7;
    int r3 = r2 >> 3;
    int ri = r3 & 1;
    int r4 = r3 >> 1;
    int og = r4 & 7;
    int m  = r4 >> 3;
    int o = og * 16 + (lane & 15);
    int kbase = ck * 32 + (lane >> 4) * 8;
    bf16x8 v;
    #pragma unroll
    for (int j = 0; j < 8; ++j) {
        int k = kbase + j;
        int i = k >> 1, ko = k & 1;
        const float* wp = w + ((size_t)(i * 128 + o) * 16 + m) * 2;
        float val;
        if (ri == 0) val = ko ? -wp[1] : wp[0];
        else         val = ko ?  wp[0] : wp[1];
        v[j] = (short)f2bf(val);
    }
    wb[r] = v;
}

// ============================================================================
// Main fused kernel: 2048 blocks x 1024 threads (16 waves), BN=16.
// og pipeline FULLY UNROLLED: static k lets the scheduler software-pipeline
// next-og weight loads (global, un-ordered by s_barrier) under current MFMAs.
// OF ping-pong: einsum(k) || irfft(k-1), 1 barrier/step, paired stores.
// ============================================================================
__global__ __launch_bounds__(1024, 2)
void spectral_mfma(const float* __restrict__ x, const bf16x8* __restrict__ wb,
                   float* __restrict__ out) {
    extern __shared__ char lds[];
    float* tabc = (float*)(lds + OF1_OFF);          // overlays OF1[0:2048]
    float* tabs = (float*)(lds + OF1_OFF + 2048);   // overlays OF1[2048:4096]
    const int tid = threadIdx.x;
    const int n0  = blockIdx.x * BN;

    // einsum/irfft mapping
    const int lane = tid & 63;
    const int wid  = tid >> 6;          // einsum: mode; irfft: n-row
    const int col  = lane & 15;
    const int kq   = lane >> 4;
    const unsigned swza = (unsigned)((col & 7) << 4);   // XF read swizzle
    const unsigned swzo = (unsigned)((col & 7) << 3);   // OF swizzle (no&7==col&7)

    // ---------- phase 0: rfft tables [t][m] (overlay OF1) ----------
    if (tid < 512) {
        int m = tid & 15, t = tid >> 4;
        float s, c;
        sincosf(0.19634954084936207f * (float)((m * t) & 31), &s, &c);
        tabc[t * 16 + m] = c;
        tabs[t * 16 + m] = s;
    }

    // per-thread irfft fragments DT[t=col | col+16][k2 = kq*8 + jj]  (16 VGPR)
    bf16x8 dtf0, dtf1;
    #pragma unroll
    for (int jm = 0; jm < 4; ++jm) {
        int m = kq * 4 + jm;
        float alpha = (m == 0) ? 0.03125f : 0.0625f;   // 1/32, 2/32
        float s, c;
        sincosf(0.19634954084936207f * (float)((m * col) & 31), &s, &c);
        dtf0[jm * 2 + 0] = (short)f2bf(alpha * c);
        dtf0[jm * 2 + 1] = (m == 0) ? (short)0 : (short)f2bf(-alpha * s);
        sincosf(0.19634954084936207f * (float)((m * (col + 16)) & 31), &s, &c);
        dtf1[jm * 2 + 0] = (short)f2bf(alpha * c);
        dtf1[jm * 2 + 1] = (m == 0) ? (short)0 : (short)f2bf(-alpha * s);
    }
    __syncthreads();

    // ---------- phase 1: folded rfft, two adjacent i-columns per thread ----------
    {
        const int nn = tid >> 6;            // 0..15
        const int i2 = (tid & 63) * 2;
        const float* xp = x + (size_t)(n0 + nn) * CC + i2;
        float2 x0  = *(const float2*)(xp);
        float2 x16 = *(const float2*)(xp + (size_t)16 * NC);
        float xrA[16], xiA[16], xrB[16], xiB[16];
        #pragma unroll
        for (int m = 0; m < 16; ++m) {
            float sgn = (m & 1) ? -1.f : 1.f;
            xrA[m] = x0.x + sgn * x16.x;
            xrB[m] = x0.y + sgn * x16.y;
            xiA[m] = 0.f; xiB[m] = 0.f;
        }
        #pragma unroll 3
        for (int t = 1; t <= 15; ++t) {
            float2 a = *(const float2*)(xp + (size_t)t * NC);
            float2 b = *(const float2*)(xp + (size_t)(32 - t) * NC);
            float ex = a.x + b.x, ey = a.y + b.y;
            float ox = a.x - b.x, oy = a.y - b.y;
            float4 c0 = *(const float4*)&tabc[t * 16 + 0];
            float4 c1 = *(const float4*)&tabc[t * 16 + 4];
            float4 c2 = *(const float4*)&tabc[t * 16 + 8];
            float4 c3 = *(const float4*)&tabc[t * 16 + 12];
            float4 s0 = *(const float4*)&tabs[t * 16 + 0];
            float4 s1 = *(const float4*)&tabs[t * 16 + 4];
            float4 s2 = *(const float4*)&tabs[t * 16 + 8];
            float4 s3 = *(const float4*)&tabs[t * 16 + 12];
            float cm[16] = {c0.x,c0.y,c0.z,c0.w, c1.x,c1.y,c1.z,c1.w,
                            c2.x,c2.y,c2.z,c2.w, c3.x,c3.y,c3.z,c3.w};
            float sm[16] = {s0.x,s0.y,s0.z,s0.w, s1.x,s1.y,s1.z,s1.w,
                            s2.x,s2.y,s2.z,s2.w, s3.x,s3.y,s3.z,s3.w};
            #pragma unroll
            for (int m = 0; m < 16; ++m) {
                xrA[m] += ex * cm[m];  xiA[m] -= ox * sm[m];
                xrB[m] += ey * cm[m];  xiB[m] -= oy * sm[m];
            }
        }
        char* xfb = lds + XF_OFF;
        const unsigned swzd = (unsigned)((nn & 7) << 4);
        #pragma unroll
        for (int m = 0; m < 16; ++m) {
            unsigned byte = ((unsigned)(m * 8192 + nn * 512 + i2 * 4)) ^ swzd;
            uint2 v2;
            v2.x = pack2(xrA[m], xiA[m]);
            v2.y = pack2(xrB[m], xiB[m]);
            *(uint2*)(xfb + byte) = v2;
        }
    }
    __syncthreads();

    // ---------- og pipeline (UNROLLED): einsum(k) || irfft(k-1), k = 0..8 ----
    char* xfb = lds + XF_OFF;
    float* outp = out + (size_t)(n0 + wid) * CC + col;
    const unsigned arow = (unsigned)(wid * 8192 + col * 512 + kq * 16);
    f32x4 sv0 = {0.f,0.f,0.f,0.f}, sv1 = {0.f,0.f,0.f,0.f};

    #pragma unroll
    for (int k = 0; k <= 8; ++k) {
        if (k < 8) {
            // einsum: OF[mode=wid], o-tile k, K=256 over (i,ri)
            char* ofb = lds + ((k & 1) ? OF1_OFF : OF0_OFF);
            const bf16x8* wog = wb + (size_t)((wid * 8 + k) * 2) * (8 * 64);
            f32x4 accR = {0.f, 0.f, 0.f, 0.f};
            f32x4 accI = {0.f, 0.f, 0.f, 0.f};
            #pragma unroll
            for (int ck = 0; ck < 8; ++ck) {
                bf16x8 af = *(const bf16x8*)(xfb + ((arow + (unsigned)(ck * 64)) ^ swza));
                bf16x8 bR = wog[(0 * 8 + ck) * 64 + lane];
                bf16x8 bI = wog[(1 * 8 + ck) * 64 + lane];
                accR = __builtin_amdgcn_mfma_f32_16x16x32_bf16(af, bR, accR, 0, 0, 0);
                accI = __builtin_amdgcn_mfma_f32_16x16x32_bf16(af, bI, accI, 0, 0, 0);
            }
            #pragma unroll
            for (int j = 0; j < 4; ++j) {
                unsigned no = (unsigned)((kq * 4 + j) * 16 + col);
                unsigned addr = no * 64u + (((unsigned)(wid * 4)) ^ ((no & 7) << 3));
                *(unsigned*)(ofb + addr) = pack2(accR[j], accI[j]);
            }
        }
        if (k > 0) {
            // irfft of o-tile (k-1); wave wid = n-row
            const int og = k - 1;
            char* ofb = lds + ((og & 1) ? OF1_OFF : OF0_OFF);
            unsigned rowb = (unsigned)((wid * 16 + col) * 64);
            bf16x4 lo = *(const bf16x4*)(ofb + rowb + (((unsigned)(kq * 16)) ^ swzo));
            bf16x4 hi = *(const bf16x4*)(ofb + rowb + (((unsigned)(kq * 16 + 8)) ^ swzo));
            bf16x8 pf;
            #pragma unroll
            for (int q = 0; q < 4; ++q) { pf[q] = lo[q]; pf[4 + q] = hi[q]; }
            f32x4 z = {0.f, 0.f, 0.f, 0.f};
            f32x4 c0 = __builtin_amdgcn_mfma_f32_16x16x32_bf16(dtf0, pf, z, 0, 0, 0);
            f32x4 c1 = __builtin_amdgcn_mfma_f32_16x16x32_bf16(dtf1, pf, z, 0, 0, 0);
            if ((og & 1) == 0) {
                sv0 = c0; sv1 = c1;           // buffer even og; store with odd og
            } else {
                float* opE = outp + (og - 1) * 16;
                float* opO = outp + og * 16;
                #pragma unroll
                for (int j = 0; j < 4; ++j) {
                    int t0 = kq * 4 + j;
                    opE[(size_t)t0 * NC]        = sv0[j];   // adjacent 64B halves
                    opO[(size_t)t0 * NC]        = c0[j];    // of one 128B line
                    opE[(size_t)(t0 + 16) * NC] = sv1[j];
                    opO[(size_t)(t0 + 16) * NC] = c1[j];
                }
            }
        }
        __syncthreads();
    }
}

// ============================================================================
// Fallback (round-1 proven kernel) — used only if ws_size < 2 MB.
// ============================================================================
#define FBN 8
#define FXST 36
__global__ __launch_bounds__(512, 2)
void spectral_fused(const float* __restrict__ x,
                    const float* __restrict__ w,
                    float* __restrict__ out) {
    extern __shared__ float flds[];
    float* xf    = flds;
    float* ftabc = flds + FBN * CC * FXST;
    float* ftabs = ftabc + 512;

    const int tid = threadIdx.x;
    const int n0  = blockIdx.x * FBN;

    {
        const int m = tid >> 5;
        const int t = tid & 31;
        const float ang = 0.19634954084936207f * (float)((m * t) & 31);
        float s, c; sincosf(ang, &s, &c);
        ftabc[tid] = c; ftabs[tid] = s;
    }
    __syncthreads();
    {
        const int i   = tid & 127;
        const int nnA = tid >> 7;
        const int nnB = nnA + 4;
        float xra[MM], xia[MM], xrb[MM], xib[MM];
        #pragma unroll
        for (int m = 0; m < MM; ++m) { xra[m]=0.f; xia[m]=0.f; xrb[m]=0.f; xib[m]=0.f; }
        const float* xA = x + (size_t)(n0 + nnA) * CC + i;
        const float* xB = x + (size_t)(n0 + nnB) * CC + i;
        for (int t = 0; t < TT; ++t) {
            const float va = xA[(size_t)t * NC];
            const float vb = xB[(size_t)t * NC];
            #pragma unroll
            for (int m = 0; m < MM; ++m) {
                const float c = ftabc[(m << 5) + t];
                const float s = ftabs[(m << 5) + t];
                xra[m] += va * c;  xia[m] -= va * s;
                xrb[m] += vb * c;  xib[m] -= vb * s;
            }
        }
        float* dA = xf + (size_t)(nnA * CC + i) * FXST;
        float* dB = xf + (size_t)(nnB * CC + i) * FXST;
        #pragma unroll
        for (int j = 0; j < 8; ++j) {
            *(float4*)(dA + 4 * j) = make_float4(xra[2*j], xia[2*j], xra[2*j+1], xia[2*j+1]);
            *(float4*)(dB + 4 * j) = make_float4(xrb[2*j], xib[2*j], xrb[2*j+1], xib[2*j+1]);
        }
    }
    __syncthreads();
    const int o   = tid & 127;
    const int nnA = tid >> 7;
    const int nnB = nnA + 4;
    float ar[MM], ai_[MM], br[MM], bi_[MM];
    #pragma unroll
    for (int m = 0; m < MM; ++m) { ar[m]=0.f; ai_[m]=0.f; br[m]=0.f; bi_[m]=0.f; }
    const float* qa0 = xf + (size_t)(nnA * CC) * FXST;
    const float* qb0 = xf + (size_t)(nnB * CC) * FXST;
    float4 wv[8];
    {
        const float4* wp = (const float4*)(w + (size_t)o * 32);
        #pragma unroll
        for (int j = 0; j < 8; ++j) wv[j] = wp[j];
    }
    for (int i = 0; i < CC; ++i) {
        float4 xa4[8], xb4[8];
        const float4* qa = (const float4*)(qa0 + i * FXST);
        const float4* qb = (const float4*)(qb0 + i * FXST);
        #pragma unroll
        for (int j = 0; j < 8; ++j) { xa4[j] = qa[j]; xb4[j] = qb[j]; }
        float4 wn[8];
        if (i + 1 < CC) {
            const float4* wp = (const float4*)(w + (size_t)((i + 1) * CC + o) * 32);
            #pragma unroll
            for (int j = 0; j < 8; ++j) wn[j] = wp[j];
        }
        #pragma unroll
        for (int j = 0; j < 8; ++j) {
            const int m0 = 2 * j, m1 = 2 * j + 1;
            ar[m0]  += xa4[j].x * wv[j].x - xa4[j].y * wv[j].y;
            ai_[m0] += xa4[j].x * wv[j].y + xa4[j].y * wv[j].x;
            br[m0]  += xb4[j].x * wv[j].x - xb4[j].y * wv[j].y;
            bi_[m0] += xb4[j].x * wv[j].y + xb4[j].y * wv[j].x;
            ar[m1]  += xa4[j].z * wv[j].z - xa4[j].w * wv[j].w;
            ai_[m1] += xa4[j].z * wv[j].w + xa4[j].w * wv[j].z;
            br[m1]  += xb4[j].z * wv[j].z - xb4[j].w * wv[j].w;
            bi_[m1] += xb4[j].z * wv[j].w + xb4[j].w * wv[j].z;
        }
        #pragma unroll
        for (int j = 0; j < 8; ++j) wv[j] = wn[j];
    }
    {
        const float inv = 1.0f / 32.0f;
        const size_t obA = (size_t)(n0 + nnA) * CC + o;
        const size_t obB = (size_t)(n0 + nnB) * CC + o;
        for (int t = 0; t < TT; ++t) {
            float accA = 0.f, accB = 0.f;
            #pragma unroll
            for (int m = 1; m < MM; ++m) {
                const float c = ftabc[(m << 5) + t];
                const float s = ftabs[(m << 5) + t];
                accA += ar[m] * c - ai_[m] * s;
                accB += br[m] * c - bi_[m] * s;
            }
            out[(size_t)t * NC + obA] = (ar[0] + 2.f * accA) * inv;
            out[(size_t)t * NC + obB] = (br[0] + 2.f * accB) * inv;
        }
    }
}

extern "C" void kernel_launch(void* const* d_in, const int* in_sizes, int n_in,
                              void* d_out, int out_size, void* d_ws, size_t ws_size,
                              hipStream_t stream) {
    (void)in_sizes; (void)n_in; (void)out_size;
    const float* x = (const float*)d_in[0];
    const float* w = (const float*)d_in[1];
    float* out     = (float*)d_out;

    if (d_ws != nullptr && ws_size >= (size_t)2 * 1024 * 1024) {
        bf16x8* wbuf = (bf16x8*)d_ws;
        hipLaunchKernelGGL(repack_w, dim3(512), dim3(256), 0, stream, w, wbuf);
        hipLaunchKernelGGL(spectral_mfma, dim3(NPT / BN), dim3(1024), LDS_BYTES, stream,
                           x, wbuf, out);
    } else {
        const size_t lds_bytes = (size_t)(FBN * CC * FXST + 1024) * sizeof(float);
        hipLaunchKernelGGL(spectral_fused, dim3(NPT / FBN), dim3(512), lds_bytes, stream,
                           x, w, out);
    }
}